// Round 1
// baseline (1278.255 us; speedup 1.0000x reference)
//
#include <hip/hip_runtime.h>
#include <hip/hip_bf16.h>
#include <stdint.h>

// GRU-style LanguageEncoder: T=64, B=256, VOCAB=32000, D=512, H=1024.
// Reference semantics: a = tanh(a_x + (r * h) @ w_h_a + b_a)  ((r*h) BEFORE matmul).
// Structure:
//   k_gather    : words_bf16[t*B+b][d] = bf16(embed[x]*(x>0))
//   k_transpose : w_i -> wit (3072x512) bf16 ; w_h -> wht (3072x1024) bf16
//   k_zero      : zero h buffer + barrier flags (+ hship, post-gemm)
//   k_gemm_gx   : gx = words @ w_i + b  (16384x3072, bf16), 128x128 MFMA tile
//   k_recur     : persistent 256-block kernel, 64 steps, 2 phases/step.
//   History (per-step): R2 RMW+fences 33us; R3 flags+fences 21.5; R6 atomic
//   reads 16.4 (atomic-pipe-bound); R8 acquire-inv cached reads 12.8;
//   R9/R10 plain sc0sc1 L3 loads, no fences: 12.4 (phase = 6.2us == 32MB of
//   16B fabric reads at ~5.2TB/s -> coherent-fabric BW bound).
//   R11: role-specialized blocks, C=32 cols/block. 4 m-groups x (32 Z + 32 A).
//   Z: W_zr (64x1024 bf16, 129KB LDS), computes z,r, stores rh + ships z(f32).
//   A: W_a (32x1024, 66KB LDS), computes a, h-update (hp stays f32 in regs),
//   stores h slab + ships h j-slice (lane-layout 16B) back to its Z partner.
//   Halves exchange-read traffic (every h byte read by 32 blocks, not 64).
//   Slab loads: issue all 32 dwordx4 up front, counted vmcnt waits (25/17/9/1)
//   tied to frags via "+v" -> 1 L3 latency per phase instead of 4 serialized.
//   Barrier: per-role monotonic flag counters, 32 slots/group, 64B stride.

#define TT 64
#define BB 256
#define DD 512
#define HH 1024
#define N3H 3072

using frag  = __attribute__((ext_vector_type(8))) short;   // 8 bf16 (4 VGPRs)
using f32x4 = __attribute__((ext_vector_type(4))) float;   // MFMA accumulator
using u32x4 = __attribute__((ext_vector_type(4))) unsigned int;

__device__ __forceinline__ uint16_t f2b(float f) {
    uint32_t u = __builtin_bit_cast(uint32_t, f);
    uint32_t r = u + 0x7FFFu + ((u >> 16) & 1u);   // round-to-nearest-even
    return (uint16_t)(r >> 16);
}
__device__ __forceinline__ float b2f(uint16_t b) {
    uint32_t u = ((uint32_t)b) << 16;
    return __builtin_bit_cast(float, u);
}

// Issue 8 x 16B L3-coherent loads (sc0 sc1: bypass L1/L2, performed at the
// coherence point) from 64B-strided addresses. NO wait — caller uses counted
// vmcnt via WAIT8 (operands tied so consumers depend on the wait, and volatile
// asm order preserves issue order => in-order vmcnt retirement math is valid).
__device__ __forceinline__ void load8_issue(const uint16_t* p, frag* f) {
    asm volatile(
        "global_load_dwordx4 %0, %8, off sc0 sc1\n\t"
        "global_load_dwordx4 %1, %8, off offset:64 sc0 sc1\n\t"
        "global_load_dwordx4 %2, %8, off offset:128 sc0 sc1\n\t"
        "global_load_dwordx4 %3, %8, off offset:192 sc0 sc1\n\t"
        "global_load_dwordx4 %4, %8, off offset:256 sc0 sc1\n\t"
        "global_load_dwordx4 %5, %8, off offset:320 sc0 sc1\n\t"
        "global_load_dwordx4 %6, %8, off offset:384 sc0 sc1\n\t"
        "global_load_dwordx4 %7, %8, off offset:448 sc0 sc1"
        : "=&v"(f[0]), "=&v"(f[1]), "=&v"(f[2]), "=&v"(f[3]),
          "=&v"(f[4]), "=&v"(f[5]), "=&v"(f[6]), "=&v"(f[7])
        : "v"(p)
        : "memory");
}
__device__ __forceinline__ void load16_l3(const void* p, u32x4* q) {
    asm volatile("global_load_dwordx4 %0, %1, off sc0 sc1"
                 : "=&v"(*q) : "v"(p) : "memory");
}
__device__ __forceinline__ void load32_l3(const void* p, f32x4* q0, f32x4* q1) {
    asm volatile("global_load_dwordx4 %0, %2, off sc0 sc1\n\t"
                 "global_load_dwordx4 %1, %2, off offset:16 sc0 sc1"
                 : "=&v"(*q0), "=&v"(*q1) : "v"(p) : "memory");
}
__device__ __forceinline__ void exch64(uint64_t* dst, uint64_t v) {
    (void)__hip_atomic_exchange(dst, v, __ATOMIC_RELAXED, __HIP_MEMORY_SCOPE_AGENT);
}
__device__ __forceinline__ uint64_t pkf(float a, float b) {
    return (uint64_t)__builtin_bit_cast(uint32_t, a) |
           ((uint64_t)__builtin_bit_cast(uint32_t, b) << 32);
}

// counted wait: outstanding <= N. Ties the 8 frags so MFMA consumers depend
// on THIS asm's outputs (rule-18-safe without sched_barrier).
#define WAIT8(N, F)                                                       \
    asm volatile("s_waitcnt vmcnt(" #N ")"                                \
                 : "+v"((F)[0]), "+v"((F)[1]), "+v"((F)[2]),              \
                   "+v"((F)[3]), "+v"((F)[4]), "+v"((F)[5]),              \
                   "+v"((F)[6]), "+v"((F)[7]))

#define ZCONSUME(KB, HF)                                                          \
    _Pragma("unroll")                                                             \
    for (int j = 0; j < 8; ++j) {                                                 \
        const uint16_t* wrow = Wh + ((KB) * 8 + j) * 32 + quad * 8;               \
        frag bz0 = *(const frag*)(wrow + l16 * LDW);                              \
        frag bz1 = *(const frag*)(wrow + (16 + l16) * LDW);                       \
        frag br0 = *(const frag*)(wrow + (32 + l16) * LDW);                       \
        frag br1 = *(const frag*)(wrow + (48 + l16) * LDW);                       \
        accz0 = __builtin_amdgcn_mfma_f32_16x16x32_bf16((HF)[j], bz0, accz0, 0, 0, 0); \
        accz1 = __builtin_amdgcn_mfma_f32_16x16x32_bf16((HF)[j], bz1, accz1, 0, 0, 0); \
        accr0 = __builtin_amdgcn_mfma_f32_16x16x32_bf16((HF)[j], br0, accr0, 0, 0, 0); \
        accr1 = __builtin_amdgcn_mfma_f32_16x16x32_bf16((HF)[j], br1, accr1, 0, 0, 0); \
    }

#define ACONSUME(KB, RF)                                                          \
    _Pragma("unroll")                                                             \
    for (int j = 0; j < 8; ++j) {                                                 \
        const uint16_t* wrow = Wh + ((KB) * 8 + j) * 32 + quad * 8;               \
        frag ba0 = *(const frag*)(wrow + l16 * LDW);                              \
        frag ba1 = *(const frag*)(wrow + (16 + l16) * LDW);                       \
        acca0 = __builtin_amdgcn_mfma_f32_16x16x32_bf16((RF)[j], ba0, acca0, 0, 0, 0); \
        acca1 = __builtin_amdgcn_mfma_f32_16x16x32_bf16((RF)[j], ba1, acca1, 0, 0, 0); \
    }

// ---------------- prep kernels ----------------

__global__ __launch_bounds__(256) void k_gather(const int* __restrict__ x,
                                                const float* __restrict__ embed,
                                                uint16_t* __restrict__ words) {
    int tid = blockIdx.x * 256 + threadIdx.x;
    int row = tid >> 6;
    int c8  = (tid & 63) << 3;
    int tok = x[row];
    float s = (tok > 0) ? 1.f : 0.f;
    const float4* src = (const float4*)(embed + (int64_t)tok * DD + c8);
    float4 v0 = src[0], v1 = src[1];
    float vals[8] = {v0.x, v0.y, v0.z, v0.w, v1.x, v1.y, v1.z, v1.w};
    union { uint16_t u[8]; uint4 q; } pk;
#pragma unroll
    for (int i = 0; i < 8; ++i) pk.u[i] = f2b(vals[i] * s);
    *(uint4*)(words + ((int64_t)row << 9) + c8) = pk.q;
}

// src (K x N) fp32 -> dst (N x K) bf16, 32x32 LDS tiles
__global__ void k_transpose(const float* __restrict__ src, uint16_t* __restrict__ dst,
                            int K, int N) {
    __shared__ float tile[32][33];
    int n0 = blockIdx.x * 32, k0 = blockIdx.y * 32;
    int tx = threadIdx.x, ty = threadIdx.y;   // (32, 8)
#pragma unroll
    for (int i = 0; i < 32; i += 8)
        tile[ty + i][tx] = src[(int64_t)(k0 + ty + i) * N + n0 + tx];
    __syncthreads();
#pragma unroll
    for (int i = 0; i < 32; i += 8)
        dst[(int64_t)(n0 + ty + i) * K + k0 + tx] = f2b(tile[tx][ty + i]);
}

__global__ void k_zero(uint4* p, int n16) {
    int i = blockIdx.x * blockDim.x + threadIdx.x;
    if (i < n16) p[i] = uint4{0u, 0u, 0u, 0u};
}

// ---------------- gx GEMM: 16384 x 3072 x 512 ----------------

__global__ __launch_bounds__(256) void k_gemm_gx(const uint16_t* __restrict__ A,
                                                 const uint16_t* __restrict__ BT,
                                                 const float* __restrict__ bias,
                                                 uint16_t* __restrict__ C) {
    __shared__ uint16_t As[128][72];
    __shared__ uint16_t Bs[128][72];
    int m0 = blockIdx.y * 128;
    int n0 = blockIdx.x * 128;
    int t = threadIdx.x;
    int wave = t >> 6, lane = t & 63, quad = lane >> 4, l16 = lane & 15;
    int wm = (wave & 1) * 64, wn = (wave >> 1) * 64;
    f32x4 acc[4][4] = {};

    int sr = t >> 1;
    int sc = (t & 1) * 32;

    for (int k0 = 0; k0 < DD; k0 += 64) {
        const uint4* ga = (const uint4*)(A + (int64_t)(m0 + sr) * DD + k0 + sc);
        uint4 a0 = ga[0], a1 = ga[1], a2 = ga[2], a3 = ga[3];
        const uint4* gb = (const uint4*)(BT + (int64_t)(n0 + sr) * DD + k0 + sc);
        uint4 b0 = gb[0], b1 = gb[1], b2 = gb[2], b3 = gb[3];
        __syncthreads();
        *(uint4*)&As[sr][sc]      = a0;
        *(uint4*)&As[sr][sc + 8]  = a1;
        *(uint4*)&As[sr][sc + 16] = a2;
        *(uint4*)&As[sr][sc + 24] = a3;
        *(uint4*)&Bs[sr][sc]      = b0;
        *(uint4*)&Bs[sr][sc + 8]  = b1;
        *(uint4*)&Bs[sr][sc + 16] = b2;
        *(uint4*)&Bs[sr][sc + 24] = b3;
        __syncthreads();
#pragma unroll
        for (int kk = 0; kk < 64; kk += 32) {
            frag af[4], bf[4];
#pragma unroll
            for (int mi = 0; mi < 4; ++mi)
                af[mi] = *(const frag*)&As[wm + mi * 16 + l16][kk + quad * 8];
#pragma unroll
            for (int ni = 0; ni < 4; ++ni)
                bf[ni] = *(const frag*)&Bs[wn + ni * 16 + l16][kk + quad * 8];
#pragma unroll
            for (int mi = 0; mi < 4; ++mi)
#pragma unroll
                for (int ni = 0; ni < 4; ++ni)
                    acc[mi][ni] = __builtin_amdgcn_mfma_f32_16x16x32_bf16(
                        af[mi], bf[ni], acc[mi][ni], 0, 0, 0);
        }
    }
#pragma unroll
    for (int ni = 0; ni < 4; ++ni) {
        int col = n0 + wn + ni * 16 + l16;
        float bv = bias[col];
#pragma unroll
        for (int mi = 0; mi < 4; ++mi)
#pragma unroll
            for (int r = 0; r < 4; ++r) {
                int row = m0 + wm + mi * 16 + quad * 4 + r;
                C[(int64_t)row * N3H + col] = f2b(acc[mi][ni][r] + bv);
            }
    }
}

// ---------------- recurrence (R11: role-specialized, C=32) ----------------
// grid (8, 32): blockIdx.x = mg*2+role (fast dim -> XCD pinning: all 32 blocks
// of one (mg,role) on one XCD). jb = blockIdx.y (0..31), j0 = 32*jb.
// LDS: Z-blocks Wzr[64][1032] bf16 (129KB), A-blocks Wa[32][1032] (66KB).
// Flags: zfl = bar + mg*512, afl = bar + 2048 + mg*512; slot jb*16 (64B apart),
// monotonic counters. Z@t waits afl>=t; A@t waits zfl>=t+1. No cycles.
// zship: Z->A per-lane 8 x f32 (z gate, exact). hship: A->Z per-lane 8 x bf16
// (h j-slice in acc layout) so Z computes rh = r*h without scalar fabric loads.

__global__ __launch_bounds__(256, 1) void k_recur(const uint16_t* __restrict__ gx,
                                                  const uint16_t* __restrict__ wht,
                                                  uint16_t* __restrict__ hbuf,
                                                  uint16_t* __restrict__ rhbuf,
                                                  float* __restrict__ zship,
                                                  uint16_t* __restrict__ hship,
                                                  unsigned int* __restrict__ bar,
                                                  float* __restrict__ out) {
    extern __shared__ uint16_t Wh[];
    const int LDW = HH + 8;
    int mg   = blockIdx.x >> 1;   // 0..3
    int role = blockIdx.x & 1;    // 0 = Z (z,r,rh), 1 = A (a, h update)
    int jb   = blockIdx.y;        // 0..31
    int j0 = jb * 32;
    int m0 = mg * 64;
    int t = threadIdx.x, wave = t >> 6, lane = t & 63, quad = lane >> 4, l16 = lane & 15;
    int brow = m0 + wave * 16 + quad * 4;

    unsigned int* zfl = bar + mg * 512;          // 32 slots x 16 uints
    unsigned int* afl = bar + 2048 + mg * 512;
    unsigned int* myf = (role == 0 ? zfl : afl) + jb * 16;

    // stage this block's w_h slice: LDS row = col-within-slice (per gate region)
    if (role == 0) {
        for (int c = t; c < 64 * 128; c += 256) {
            int row = c >> 7, off = (c & 127) << 3;
            int o = (row < 32) ? (j0 + row) : (HH + j0 + row - 32);
            *(uint4*)(Wh + row * LDW + off) = *(const uint4*)(wht + (int64_t)o * HH + off);
        }
    } else {
        for (int c = t; c < 32 * 128; c += 256) {
            int row = c >> 7, off = (c & 127) << 3;
            int o = 2 * HH + j0 + row;
            *(uint4*)(Wh + row * LDW + off) = *(const uint4*)(wht + (int64_t)o * HH + off);
        }
    }
    __syncthreads();

    auto wait_all = [&](unsigned int* fl, unsigned int ph) {
        if (wave == 0) {
            long guard = 0;
            for (;;) {
                unsigned int v = __hip_atomic_load(&fl[(lane & 31) * 16], __ATOMIC_RELAXED,
                                                   __HIP_MEMORY_SCOPE_AGENT);
                if (__all((int)(v >= ph))) break;
                __builtin_amdgcn_s_sleep(1);
                if (++guard > (1L << 13)) break;   // fail fast (absmax), never wedge
            }
        }
        __syncthreads();
    };
    auto arrive = [&]() {
        __syncthreads();   // drains data RMWs (vmcnt 0) before the flag RMW
        if (t == 0)
            (void)__hip_atomic_fetch_add(myf, 1u, __ATOMIC_RELAXED, __HIP_MEMORY_SCOPE_AGENT);
    };
    // pack this lane's bf16 with lanes l16^1, l16^2 -> one u64 (4 adjacent cols)
    // exchanged to the coherence point by the (l16%4==0) lane.
    auto store4 = [&](uint16_t* base, int row, int jc4, uint32_t mine) {
        uint32_t p2 = mine | (((uint32_t)__shfl_xor((int)mine, 1)) << 16);
        uint32_t hi = (uint32_t)__shfl_xor((int)p2, 2);
        if ((l16 & 3) == 0) {
            uint64_t p4 = (uint64_t)p2 | ((uint64_t)hi << 32);
            uint64_t* dst = (uint64_t*)base + (int64_t)row * (HH / 4) + (jc4 >> 2);
            (void)__hip_atomic_exchange(dst, p4, __ATOMIC_RELAXED, __HIP_MEMORY_SCOPE_AGENT);
        }
    };

    size_t sidx = (size_t)((mg * 32 + jb) * 256 + t);   // lane-layout ship slot

    if (role == 0) {
        // ---------------- Z-blocks: z, r, rh ----------------
        const uint16_t* harow = hbuf + (int64_t)(m0 + wave * 16 + l16) * HH + quad * 8;
        const uint16_t* hs = hship + (sidx << 3);       // 8 bf16 = 16B
        uint64_t* zb = (uint64_t*)zship + (sidx << 2);  // 8 f32  = 32B
        for (int step = 0; step < TT; ++step) {
            // gx prefetch (immutable, cached) - hidden under flag poll
            float gzv[2][4], grv[2][4];
            const uint16_t* gxrow = gx + (int64_t)step * BB * N3H;
#pragma unroll
            for (int ni = 0; ni < 2; ++ni)
#pragma unroll
                for (int r = 0; r < 4; ++r) {
                    const uint16_t* g = gxrow + (int64_t)(brow + r) * N3H + j0 + ni * 16 + l16;
                    gzv[ni][r] = b2f(g[0]);
                    grv[ni][r] = b2f(g[HH]);
                }
            if (step > 0) wait_all(afl, (unsigned)step);
            asm volatile("s_waitcnt vmcnt(0)" ::: "memory");   // clean vmcnt slate
            // issue all slab loads (32) + h j-slice ship (1): in-flight together
            frag h0[8], h1[8], h2[8], h3[8];
            load8_issue(harow,       h0);
            load8_issue(harow + 256, h1);
            load8_issue(harow + 512, h2);
            load8_issue(harow + 768, h3);
            u32x4 hq;
            load16_l3(hs, &hq);
            f32x4 accz0 = {}, accz1 = {}, accr0 = {}, accr1 = {};
            WAIT8(25, h0); ZCONSUME(0, h0);
            WAIT8(17, h1); ZCONSUME(1, h1);
            WAIT8(9,  h2); ZCONSUME(2, h2);
            WAIT8(1,  h3); ZCONSUME(3, h3);
            asm volatile("s_waitcnt vmcnt(0)" : "+v"(hq));
            float zf[2][4];
#pragma unroll
            for (int ni = 0; ni < 2; ++ni)
#pragma unroll
                for (int r = 0; r < 4; ++r) {
                    float zp = gzv[ni][r] + ((ni == 0) ? accz0 : accz1)[r];  // bias in gx
                    float rp = grv[ni][r] + ((ni == 0) ? accr0 : accr1)[r];
                    float z  = 1.f / (1.f + __expf(-zp));
                    float rg = 1.f / (1.f + __expf(-rp));
                    zf[ni][r] = z;
                    uint32_t w = hq[ni * 2 + (r >> 1)];
                    uint16_t hb16 = (r & 1) ? (uint16_t)(w >> 16) : (uint16_t)(w & 0xFFFFu);
                    store4(rhbuf, brow + r, j0 + ni * 16 + (l16 & ~3),
                           (uint32_t)f2b(rg * b2f(hb16)));
                }
            // ship z exactly (f32) to the A partner block
            exch64(zb + 0, pkf(zf[0][0], zf[0][1]));
            exch64(zb + 1, pkf(zf[0][2], zf[0][3]));
            exch64(zb + 2, pkf(zf[1][0], zf[1][1]));
            exch64(zb + 3, pkf(zf[1][2], zf[1][3]));
            arrive();
        }
    } else {
        // ---------------- A-blocks: a, h update, osum ----------------
        const uint16_t* rharow = rhbuf + (int64_t)(m0 + wave * 16 + l16) * HH + quad * 8;
        const float* zsrc = zship + (sidx << 3);
        uint64_t* hsb = (uint64_t*)hship + (sidx << 1);
        float hp[2][4] = {}, osum[2][4] = {};
        for (int step = 0; step < TT; ++step) {
            float gav[2][4];
            const uint16_t* gxrow = gx + (int64_t)step * BB * N3H;
#pragma unroll
            for (int ni = 0; ni < 2; ++ni)
#pragma unroll
                for (int r = 0; r < 4; ++r)
                    gav[ni][r] = b2f(gxrow[(int64_t)(brow + r) * N3H + 2 * HH + j0 + ni * 16 + l16]);
            wait_all(zfl, (unsigned)(step + 1));
            asm volatile("s_waitcnt vmcnt(0)" ::: "memory");
            frag rf0[8], rf1[8], rf2[8], rf3[8];
            load8_issue(rharow,       rf0);
            load8_issue(rharow + 256, rf1);
            load8_issue(rharow + 512, rf2);
            load8_issue(rharow + 768, rf3);
            f32x4 zq0, zq1;
            load32_l3(zsrc, &zq0, &zq1);
            f32x4 acca0 = {}, acca1 = {};
            WAIT8(26, rf0); ACONSUME(0, rf0);
            WAIT8(18, rf1); ACONSUME(1, rf1);
            WAIT8(10, rf2); ACONSUME(2, rf2);
            WAIT8(2,  rf3); ACONSUME(3, rf3);
            asm volatile("s_waitcnt vmcnt(0)" : "+v"(zq0), "+v"(zq1));
            uint16_t hb[2][4];
#pragma unroll
            for (int ni = 0; ni < 2; ++ni)
#pragma unroll
                for (int r = 0; r < 4; ++r) {
                    float a = tanhf(gav[ni][r] + ((ni == 0) ? acca0 : acca1)[r]);
                    float z = (ni == 0) ? zq0[r] : zq1[r];
                    float hn = (1.f - z) * hp[ni][r] + z * a;
                    osum[ni][r] += hn;
                    hp[ni][r] = hn;   // own slice stays f32 in regs (as before)
                    hb[ni][r] = f2b(hn);
                    store4(hbuf, brow + r, j0 + ni * 16 + (l16 & ~3), (uint32_t)hb[ni][r]);
                }
            // ship h j-slice (acc layout, bf16) back to the Z partner block
            exch64(hsb + 0, (uint64_t)(hb[0][0] | ((uint32_t)hb[0][1] << 16)) |
                            ((uint64_t)(hb[0][2] | ((uint32_t)hb[0][3] << 16)) << 32));
            exch64(hsb + 1, (uint64_t)(hb[1][0] | ((uint32_t)hb[1][1] << 16)) |
                            ((uint64_t)(hb[1][2] | ((uint32_t)hb[1][3] << 16)) << 32));
            arrive();
        }
#pragma unroll
        for (int ni = 0; ni < 2; ++ni)
#pragma unroll
            for (int r = 0; r < 4; ++r)
                out[(int64_t)(brow + r) * HH + j0 + ni * 16 + l16] = osum[ni][r];
    }
}

// ---------------- launch ----------------

extern "C" void kernel_launch(void* const* d_in, const int* in_sizes, int n_in,
                              void* d_out, int out_size, void* d_ws, size_t ws_size,
                              hipStream_t stream) {
    const int*   x     = (const int*)d_in[0];
    const float* embed = (const float*)d_in[1];
    const float* w_i   = (const float*)d_in[2];
    const float* w_h   = (const float*)d_in[3];
    const float* bias  = (const float*)d_in[4];
    float* out = (float*)d_out;

    char* ws = (char*)d_ws;
    uint16_t* gx    = (uint16_t*)(ws);                 // 16384*3072*2 = 100663296
    uint16_t* wit   = (uint16_t*)(ws + 100663296);     // 3072*512*2  =   3145728
    uint16_t* wht   = (uint16_t*)(ws + 103809024);     // 3072*1024*2 =   6291456
    uint16_t* words = (uint16_t*)(ws + 110100480);     // 16384*512*2 =  16777216
    // words is dead after k_gemm_gx -> reuse its space for the ship buffers:
    float*    zship = (float*)(ws + 110100480);        // 4*32*256*8*4 = 1048576
    uint16_t* hship = (uint16_t*)(ws + 111149056);     // 4*32*256*8*2 =  524288
    uint16_t* hbuf  = (uint16_t*)(ws + 126877696);     // 256*1024*2  =    524288
    uint16_t* rhbuf = (uint16_t*)(ws + 127401984);     // 256*1024*2  =    524288
    unsigned int* flags = (unsigned int*)(ws + 127926272); // 16384 B

    k_gather<<<4096, 256, 0, stream>>>(x, embed, words);
    k_transpose<<<dim3(96, 16), dim3(32, 8), 0, stream>>>(w_i, wit, DD, N3H);
    k_transpose<<<dim3(96, 32), dim3(32, 8), 0, stream>>>(w_h, wht, HH, N3H);
    // zero hbuf + rhbuf + flags (contiguous 1048576 + 16384 bytes)
    k_zero<<<261, 256, 0, stream>>>((uint4*)(ws + 126877696), (1048576 + 16384) / 16);
    k_gemm_gx<<<dim3(24, 128), 256, 0, stream>>>(words, wit, bias, gx);
    // hship must read as zeros at step 0; it aliases words, so zero AFTER gemm
    k_zero<<<128, 256, 0, stream>>>((uint4*)(ws + 111149056), 524288 / 16);
    k_recur<<<dim3(8, 32), 256, 64 * (HH + 8) * 2, stream>>>(gx, wht, hbuf, rhbuf,
                                                             zship, hship, flags, out);
}

// Round 2
// 1004.716 us; speedup vs baseline: 1.2723x; 1.2723x over previous
//
#include <hip/hip_runtime.h>
#include <hip/hip_bf16.h>
#include <stdint.h>

// GRU-style LanguageEncoder: T=64, B=256, VOCAB=32000, D=512, H=1024.
// Reference semantics: a = tanh(a_x + (r * h) @ w_h_a + b_a)  ((r*h) BEFORE matmul).
// Structure:
//   k_gather    : words_bf16[t*B+b][d] = bf16(embed[x]*(x>0))
//   k_transpose : w_i -> wit (3072x512) bf16 ; w_h -> wht (3072x1024) bf16
//   k_zero      : zero h buffer + barrier flags (+ L2-shadow bufs, post-gemm)
//   k_gemm_gx   : gx = words @ w_i + b  (16384x3072, bf16), 128x128 MFMA tile
//   k_recur     : persistent 256-block kernel, 64 steps, 2 phases/step.
//   History (per-step): R2 RMW+fences 33us; R3 flags+fences 21.5; R6 atomic
//   reads 16.4 (atomic-pipe-bound); R8 acquire-inv cached reads 12.8;
//   R9/R10 plain sc0sc1 L3 loads, no fences: 12.4.
//   R11 role-split FAILED (17.5/step): (a) AoS ship exchanges -> 32B-granule
//   write amplification (WRITE_SIZE 5.8x), (b) grid put each role-group on ONE
//   XCD -> only 4 fabric read ports active per phase. Lesson: R10's 6.2us/phase
//   = 4MB/XCD/phase ~= 650 GB/s PER-XCD fabric port limit, all 8 ports busy.
//   R12: back to R10 single-role structure, plus:
//   (1) XCD-local L2 path: jb<32 of each group pinned to XCD mg, jb>=32 to
//       mg+4 (contiguous halves). store4 dual-writes: fabric exchange (remote
//       readers) + plain u64 store to shadow hbufL2/rhbufL2 (same layout; 32B
//       stripes pair within halves so no cross-XCD line sharing). Readers
//       publish s_getreg(XCC_ID) to a table (init barrier), classify each
//       512-col half: local -> sc0-only loads (L1-bypass, L2-hit; writer and
//       reader share the XCD's L2), remote -> sc0sc1 fabric as before.
//       Correct under ANY block->XCD mapping (runtime detect + fabric fallback).
//   (2) counted-vmcnt: issue all 32 slab loads, wait vmcnt(24/16/8/0) ->
//       1 L3 round trip per phase instead of 4 serialized.

#define TT 64
#define BB 256
#define DD 512
#define HH 1024
#define N3H 3072

using frag  = __attribute__((ext_vector_type(8))) short;   // 8 bf16 (4 VGPRs)
using f32x4 = __attribute__((ext_vector_type(4))) float;   // MFMA accumulator

__device__ __forceinline__ uint16_t f2b(float f) {
    uint32_t u = __builtin_bit_cast(uint32_t, f);
    uint32_t r = u + 0x7FFFu + ((u >> 16) & 1u);   // round-to-nearest-even
    return (uint16_t)(r >> 16);
}
__device__ __forceinline__ float b2f(uint16_t b) {
    uint32_t u = ((uint32_t)b) << 16;
    return __builtin_bit_cast(float, u);
}

// Issue 8 x 16B L3-coherent loads (sc0 sc1: bypass L1/L2, performed at the
// coherence point) from 64B-strided addresses. NO wait - caller uses counted
// vmcnt via WAIT8. gfx950 asm operand order: offset:N BEFORE cache flags.
__device__ __forceinline__ void load8_issue(const uint16_t* p, frag* f) {
    asm volatile(
        "global_load_dwordx4 %0, %8, off sc0 sc1\n\t"
        "global_load_dwordx4 %1, %8, off offset:64 sc0 sc1\n\t"
        "global_load_dwordx4 %2, %8, off offset:128 sc0 sc1\n\t"
        "global_load_dwordx4 %3, %8, off offset:192 sc0 sc1\n\t"
        "global_load_dwordx4 %4, %8, off offset:256 sc0 sc1\n\t"
        "global_load_dwordx4 %5, %8, off offset:320 sc0 sc1\n\t"
        "global_load_dwordx4 %6, %8, off offset:384 sc0 sc1\n\t"
        "global_load_dwordx4 %7, %8, off offset:448 sc0 sc1"
        : "=&v"(f[0]), "=&v"(f[1]), "=&v"(f[2]), "=&v"(f[3]),
          "=&v"(f[4]), "=&v"(f[5]), "=&v"(f[6]), "=&v"(f[7])
        : "v"(p)
        : "memory");
}
// sc0 only: bypass L1, served by this XCD's L2 (valid when the writer shares
// the XCD - its normal stores were drained to L2 before its flag RMW).
__device__ __forceinline__ void load8_issue_loc(const uint16_t* p, frag* f) {
    asm volatile(
        "global_load_dwordx4 %0, %8, off sc0\n\t"
        "global_load_dwordx4 %1, %8, off offset:64 sc0\n\t"
        "global_load_dwordx4 %2, %8, off offset:128 sc0\n\t"
        "global_load_dwordx4 %3, %8, off offset:192 sc0\n\t"
        "global_load_dwordx4 %4, %8, off offset:256 sc0\n\t"
        "global_load_dwordx4 %5, %8, off offset:320 sc0\n\t"
        "global_load_dwordx4 %6, %8, off offset:384 sc0\n\t"
        "global_load_dwordx4 %7, %8, off offset:448 sc0"
        : "=&v"(f[0]), "=&v"(f[1]), "=&v"(f[2]), "=&v"(f[3]),
          "=&v"(f[4]), "=&v"(f[5]), "=&v"(f[6]), "=&v"(f[7])
        : "v"(p)
        : "memory");
}

// counted wait: outstanding <= N. Ties the 8 frags so MFMA consumers depend
// on THIS asm's outputs (rule-18-safe without sched_barrier).
#define WAIT8(N, F)                                                       \
    asm volatile("s_waitcnt vmcnt(" #N ")"                                \
                 : "+v"((F)[0]), "+v"((F)[1]), "+v"((F)[2]),              \
                   "+v"((F)[3]), "+v"((F)[4]), "+v"((F)[5]),              \
                   "+v"((F)[6]), "+v"((F)[7]))

#define ZCON(KB, HF)                                                              \
    _Pragma("unroll")                                                             \
    for (int j = 0; j < 8; ++j) {                                                 \
        int kk = (KB) * 8 + j;                                                    \
        frag b0 = *(const frag*)(Wh + (l16)      * LDW + kk * 32 + quad * 8);     \
        frag b1 = *(const frag*)(Wh + (16 + l16) * LDW + kk * 32 + quad * 8);     \
        acc0 = __builtin_amdgcn_mfma_f32_16x16x32_bf16((HF)[j], b0, acc0, 0, 0, 0); \
        acc1 = __builtin_amdgcn_mfma_f32_16x16x32_bf16((HF)[j], b1, acc1, 0, 0, 0); \
    }

#define ACON(KB, RF)                                                              \
    _Pragma("unroll")                                                             \
    for (int j = 0; j < 8; ++j) {                                                 \
        int kk = (KB) * 8 + j;                                                    \
        frag b2 = *(const frag*)(Wh + (32 + l16) * LDW + kk * 32 + quad * 8);     \
        acc2 = __builtin_amdgcn_mfma_f32_16x16x32_bf16((RF)[j], b2, acc2, 0, 0, 0); \
    }

// ---------------- prep kernels ----------------

__global__ __launch_bounds__(256) void k_gather(const int* __restrict__ x,
                                                const float* __restrict__ embed,
                                                uint16_t* __restrict__ words) {
    int tid = blockIdx.x * 256 + threadIdx.x;
    int row = tid >> 6;
    int c8  = (tid & 63) << 3;
    int tok = x[row];
    float s = (tok > 0) ? 1.f : 0.f;
    const float4* src = (const float4*)(embed + (int64_t)tok * DD + c8);
    float4 v0 = src[0], v1 = src[1];
    float vals[8] = {v0.x, v0.y, v0.z, v0.w, v1.x, v1.y, v1.z, v1.w};
    union { uint16_t u[8]; uint4 q; } pk;
#pragma unroll
    for (int i = 0; i < 8; ++i) pk.u[i] = f2b(vals[i] * s);
    *(uint4*)(words + ((int64_t)row << 9) + c8) = pk.q;
}

// src (K x N) fp32 -> dst (N x K) bf16, 32x32 LDS tiles
__global__ void k_transpose(const float* __restrict__ src, uint16_t* __restrict__ dst,
                            int K, int N) {
    __shared__ float tile[32][33];
    int n0 = blockIdx.x * 32, k0 = blockIdx.y * 32;
    int tx = threadIdx.x, ty = threadIdx.y;   // (32, 8)
#pragma unroll
    for (int i = 0; i < 32; i += 8)
        tile[ty + i][tx] = src[(int64_t)(k0 + ty + i) * N + n0 + tx];
    __syncthreads();
#pragma unroll
    for (int i = 0; i < 32; i += 8)
        dst[(int64_t)(n0 + ty + i) * K + k0 + tx] = f2b(tile[tx][ty + i]);
}

__global__ void k_zero(uint4* p, int n16) {
    int i = blockIdx.x * blockDim.x + threadIdx.x;
    if (i < n16) p[i] = uint4{0u, 0u, 0u, 0u};
}

// ---------------- gx GEMM: 16384 x 3072 x 512 ----------------

__global__ __launch_bounds__(256) void k_gemm_gx(const uint16_t* __restrict__ A,
                                                 const uint16_t* __restrict__ BT,
                                                 const float* __restrict__ bias,
                                                 uint16_t* __restrict__ C) {
    __shared__ uint16_t As[128][72];
    __shared__ uint16_t Bs[128][72];
    int m0 = blockIdx.y * 128;
    int n0 = blockIdx.x * 128;
    int t = threadIdx.x;
    int wave = t >> 6, lane = t & 63, quad = lane >> 4, l16 = lane & 15;
    int wm = (wave & 1) * 64, wn = (wave >> 1) * 64;
    f32x4 acc[4][4] = {};

    int sr = t >> 1;
    int sc = (t & 1) * 32;

    for (int k0 = 0; k0 < DD; k0 += 64) {
        const uint4* ga = (const uint4*)(A + (int64_t)(m0 + sr) * DD + k0 + sc);
        uint4 a0 = ga[0], a1 = ga[1], a2 = ga[2], a3 = ga[3];
        const uint4* gb = (const uint4*)(BT + (int64_t)(n0 + sr) * DD + k0 + sc);
        uint4 b0 = gb[0], b1 = gb[1], b2 = gb[2], b3 = gb[3];
        __syncthreads();
        *(uint4*)&As[sr][sc]      = a0;
        *(uint4*)&As[sr][sc + 8]  = a1;
        *(uint4*)&As[sr][sc + 16] = a2;
        *(uint4*)&As[sr][sc + 24] = a3;
        *(uint4*)&Bs[sr][sc]      = b0;
        *(uint4*)&Bs[sr][sc + 8]  = b1;
        *(uint4*)&Bs[sr][sc + 16] = b2;
        *(uint4*)&Bs[sr][sc + 24] = b3;
        __syncthreads();
#pragma unroll
        for (int kk = 0; kk < 64; kk += 32) {
            frag af[4], bf[4];
#pragma unroll
            for (int mi = 0; mi < 4; ++mi)
                af[mi] = *(const frag*)&As[wm + mi * 16 + l16][kk + quad * 8];
#pragma unroll
            for (int ni = 0; ni < 4; ++ni)
                bf[ni] = *(const frag*)&Bs[wn + ni * 16 + l16][kk + quad * 8];
#pragma unroll
            for (int mi = 0; mi < 4; ++mi)
#pragma unroll
                for (int ni = 0; ni < 4; ++ni)
                    acc[mi][ni] = __builtin_amdgcn_mfma_f32_16x16x32_bf16(
                        af[mi], bf[ni], acc[mi][ni], 0, 0, 0);
        }
    }
#pragma unroll
    for (int ni = 0; ni < 4; ++ni) {
        int col = n0 + wn + ni * 16 + l16;
        float bv = bias[col];
#pragma unroll
        for (int mi = 0; mi < 4; ++mi)
#pragma unroll
            for (int r = 0; r < 4; ++r) {
                int row = m0 + wm + mi * 16 + quad * 4 + r;
                C[(int64_t)row * N3H + col] = f2b(acc[mi][ni][r] + bv);
            }
    }
}

// ---------------- recurrence (R12) ----------------
// grid (8, 32): x = mgx in [0,8): mg = mgx&3, half = mgx>>2; jb = half*32 + y.
// linear id = mgx + 8*y -> measured XCD = mgx: group mg's jb<32 on XCD mg,
// jb>=32 on XCD mg+4 (contiguous halves). LDS: Wh[48][1032] bf16 (99KB).
// Flags: one 4B slot per block, 64B apart; group mg owns bar[mg*1024 + jb*16].

__global__ __launch_bounds__(256, 1) void k_recur(const uint16_t* __restrict__ gx,
                                                  const uint16_t* __restrict__ wht,
                                                  uint16_t* __restrict__ hbuf,
                                                  uint16_t* __restrict__ rhbuf,
                                                  uint16_t* __restrict__ hbufL2,
                                                  uint16_t* __restrict__ rhbufL2,
                                                  unsigned int* __restrict__ xtab,
                                                  unsigned int* __restrict__ bar,
                                                  unsigned int* __restrict__ bar2,
                                                  float* __restrict__ out) {
    extern __shared__ uint16_t Wh[];           // 48 rows x 1032 (1024 + 8 pad)
    const int LDW = HH + 8;
    int mgx = blockIdx.x;                      // 0..7
    int mg  = mgx & 3;
    int jb  = (mgx >> 2) * 32 + blockIdx.y;    // 0..63
    int j0 = jb * 16;
    int m0 = mg * 64;
    int t = threadIdx.x, wave = t >> 6, lane = t & 63, quad = lane >> 4, l16 = lane & 15;

    // load w_h slice: gathered rows s*16+i  <-  wht row s*HH + j0 + i
    for (int c = t; c < 48 * 128; c += 256) {
        int row = c >> 7;
        int off = (c & 127) << 3;
        int s = row >> 4, i = row & 15;
        *(uint4*)(Wh + row * LDW + off) =
            *(const uint4*)(wht + (int64_t)(s * HH + j0 + i) * HH + off);
    }

    // ---- publish my XCD id, init barrier, classify column halves ----
    unsigned int myxcd;
    asm("s_getreg_b32 %0, hwreg(HW_REG_XCC_ID)" : "=s"(myxcd));
    if (t == 0)
        (void)__hip_atomic_exchange(&xtab[mg * 64 + jb], myxcd, __ATOMIC_RELAXED,
                                    __HIP_MEMORY_SCOPE_AGENT);
    __syncthreads();
    if (t == 0)
        (void)__hip_atomic_fetch_add(&bar2[mg * 1024 + jb * 16], 1u, __ATOMIC_RELAXED,
                                     __HIP_MEMORY_SCOPE_AGENT);
    if (wave == 0) {
        long guard = 0;
        for (;;) {
            unsigned int v = __hip_atomic_load(&bar2[mg * 1024 + lane * 16],
                                               __ATOMIC_RELAXED, __HIP_MEMORY_SCOPE_AGENT);
            if (__all((int)(v >= 1u))) break;
            __builtin_amdgcn_s_sleep(1);
            if (++guard > (1L << 13)) break;
        }
    }
    __syncthreads();
    bool loc01, loc23;     // cols 0..511 / 512..1023 writers all share my XCD?
    {
        unsigned int tv;
        asm volatile("global_load_dword %0, %1, off sc0 sc1\n\t"
                     "s_waitcnt vmcnt(0)"
                     : "=v"(tv) : "v"(xtab + mg * 64 + lane) : "memory");
        unsigned int c0 = (unsigned int)__shfl((int)tv, 0);
        unsigned int c1 = (unsigned int)__shfl((int)tv, 32);
        bool eq = tv == ((lane < 32) ? c0 : c1);
        uint64_t bal = __ballot(eq);
        loc01 = ((bal & 0xFFFFFFFFull) == 0xFFFFFFFFull) && (c0 == myxcd);
        loc23 = ((bal >> 32) == 0xFFFFFFFFull) && (c1 == myxcd);
    }

    float hp[4]   = {0.f, 0.f, 0.f, 0.f};
    float zg[4];
    float osum[4] = {0.f, 0.f, 0.f, 0.f};
    int brow = m0 + wave * 16 + quad * 4;
    int jcol = j0 + l16;
    const int jc4 = j0 + (l16 & ~3);         // 4-col pack base
    unsigned int* flags = bar + mg * 1024;   // 64 slots x 64B stride
    unsigned int phase = 0;

    // A-operand bases (this lane's MFMA A rows): fabric copy + L2 shadow copy
    const int64_t arow = (int64_t)(m0 + wave * 16 + l16) * HH + quad * 8;
    const uint16_t* harow   = hbuf    + arow;
    const uint16_t* harowL  = hbufL2  + arow;
    const uint16_t* rharow  = rhbuf   + arow;
    const uint16_t* rharowL = rhbufL2 + arow;

    auto bar_arrive = [&]() {
        __syncthreads();   // drains data stores/RMWs (vmcnt 0) before flag RMW
        if (t == 0)
            (void)__hip_atomic_fetch_add(&flags[jb * 16], 1u, __ATOMIC_RELAXED,
                                         __HIP_MEMORY_SCOPE_AGENT);
    };
    auto bar_wait = [&](unsigned int ph) {
        if (wave == 0) {
            long guard = 0;
            for (;;) {
                unsigned int v = __hip_atomic_load(&flags[lane * 16], __ATOMIC_RELAXED,
                                                   __HIP_MEMORY_SCOPE_AGENT);
                if (__all((int)(v >= ph))) break;
                __builtin_amdgcn_s_sleep(1);
                if (++guard > (1L << 13)) break;   // fail fast (absmax), never wedge
            }
        }
        __syncthreads();
    };

    // pack this lane's value with lanes l16^1, l16^2 -> one uint64 (4 adjacent
    // cols). Dual write: fabric exchange (remote readers) + plain store to the
    // L2 shadow (same-XCD readers; stripes pair within halves, no cross-XCD
    // line sharing, so L2 write-back is always safe).
    auto store4 = [&](uint16_t* base, uint16_t* baseL2, int r, uint32_t mine) {
        uint32_t p2 = mine | (((uint32_t)__shfl_xor((int)mine, 1)) << 16);
        uint32_t hi = (uint32_t)__shfl_xor((int)p2, 2);
        if ((l16 & 3) == 0) {
            uint64_t p4 = (uint64_t)p2 | ((uint64_t)hi << 32);
            int64_t idx = (int64_t)(brow + r) * (HH / 4) + (jc4 >> 2);
            (void)__hip_atomic_exchange((uint64_t*)base + idx, p4, __ATOMIC_RELAXED,
                                        __HIP_MEMORY_SCOPE_AGENT);
            *((uint64_t*)baseL2 + idx) = p4;
        }
    };

    for (int step = 0; step < TT; ++step) {
        // ---- barrier: h(step) fully written by all blocks in m-group ----
        if (step > 0) bar_arrive();

        // prefetch this step's gx scalars (immutable, cached) - issued between
        // arrive and wait to hide under the poll
        uint16_t gzv[4], grv[4], gav[4];
        {
            const uint16_t* gxrow = gx + (int64_t)step * BB * N3H;
#pragma unroll
            for (int r = 0; r < 4; ++r) {
                const uint16_t* g = gxrow + (int64_t)(brow + r) * N3H + jcol;
                gzv[r] = g[0]; grv[r] = g[HH]; gav[r] = g[2 * HH];
            }
        }

        if (step > 0) bar_wait(++phase);
        asm volatile("s_waitcnt vmcnt(0)" ::: "memory");   // clean vmcnt slate

        // ---- phase Z: h @ w_h_zr (acc0 = z-col, acc1 = r-col) ----
        {
            frag h0[8], h1[8], h2[8], h3[8];
            if (loc01) { load8_issue_loc(harowL,       h0); load8_issue_loc(harowL + 256, h1); }
            else       { load8_issue(harow,            h0); load8_issue(harow + 256,      h1); }
            if (loc23) { load8_issue_loc(harowL + 512, h2); load8_issue_loc(harowL + 768, h3); }
            else       { load8_issue(harow + 512,      h2); load8_issue(harow + 768,      h3); }
            f32x4 acc0 = {}, acc1 = {};
            WAIT8(24, h0); ZCON(0, h0);
            WAIT8(16, h1); ZCON(1, h1);
            WAIT8(8,  h2); ZCON(2, h2);
            WAIT8(0,  h3); ZCON(3, h3);
#pragma unroll
            for (int r = 0; r < 4; ++r) {
                float zp = b2f(gzv[r]) + acc0[r];        // bias folded into gx
                float rp = b2f(grv[r]) + acc1[r];
                float z  = 1.f / (1.f + __expf(-zp));
                float rg = 1.f / (1.f + __expf(-rp));
                zg[r] = z;
                store4(rhbuf, rhbufL2, r, (uint32_t)f2b(rg * hp[r]));
            }
        }

        // ---- barrier: rh fully written by all blocks in m-group ----
        bar_arrive();
        bar_wait(++phase);
        asm volatile("s_waitcnt vmcnt(0)" ::: "memory");   // clean vmcnt slate

        // ---- phase A: rh @ w_h_a (acc2), gate + h update ----
        {
            frag rf0[8], rf1[8], rf2[8], rf3[8];
            if (loc01) { load8_issue_loc(rharowL,       rf0); load8_issue_loc(rharowL + 256, rf1); }
            else       { load8_issue(rharow,            rf0); load8_issue(rharow + 256,      rf1); }
            if (loc23) { load8_issue_loc(rharowL + 512, rf2); load8_issue_loc(rharowL + 768, rf3); }
            else       { load8_issue(rharow + 512,      rf2); load8_issue(rharow + 768,      rf3); }
            f32x4 acc2 = {};
            WAIT8(24, rf0); ACON(0, rf0);
            WAIT8(16, rf1); ACON(1, rf1);
            WAIT8(8,  rf2); ACON(2, rf2);
            WAIT8(0,  rf3); ACON(3, rf3);
#pragma unroll
            for (int r = 0; r < 4; ++r) {
                float a  = tanhf(b2f(gav[r]) + acc2[r]);
                float hn = (1.f - zg[r]) * hp[r] + zg[r] * a;
                osum[r] += hn;
                hp[r] = hn;
                store4(hbuf, hbufL2, r, (uint32_t)f2b(hn));
            }
        }
    }
#pragma unroll
    for (int r = 0; r < 4; ++r)
        out[(int64_t)(brow + r) * HH + jcol] = osum[r];
}

// ---------------- launch ----------------

extern "C" void kernel_launch(void* const* d_in, const int* in_sizes, int n_in,
                              void* d_out, int out_size, void* d_ws, size_t ws_size,
                              hipStream_t stream) {
    const int*   x     = (const int*)d_in[0];
    const float* embed = (const float*)d_in[1];
    const float* w_i   = (const float*)d_in[2];
    const float* w_h   = (const float*)d_in[3];
    const float* bias  = (const float*)d_in[4];
    float* out = (float*)d_out;

    char* ws = (char*)d_ws;
    uint16_t* gx    = (uint16_t*)(ws);                 // 16384*3072*2 = 100663296
    uint16_t* wit   = (uint16_t*)(ws + 100663296);     // 3072*512*2  =   3145728
    uint16_t* wht   = (uint16_t*)(ws + 103809024);     // 3072*1024*2 =   6291456
    uint16_t* words = (uint16_t*)(ws + 110100480);     // 16384*512*2 =  16777216
    // words is dead after k_gemm_gx -> reuse its space for the L2 shadows:
    uint16_t* hbufL2  = (uint16_t*)(ws + 110100480);   // 256*1024*2 = 524288
    uint16_t* rhbufL2 = (uint16_t*)(ws + 110624768);   // 256*1024*2 = 524288
    unsigned int* bar2 = (unsigned int*)(ws + 111149056); // 16384
    unsigned int* xtab = (unsigned int*)(ws + 111165440); // 1024 (pad 4096)
    uint16_t* hbuf  = (uint16_t*)(ws + 126877696);     // 256*1024*2  =    524288
    uint16_t* rhbuf = (uint16_t*)(ws + 127401984);     // 256*1024*2  =    524288
    unsigned int* flags = (unsigned int*)(ws + 127926272); // 16384 B

    k_gather<<<4096, 256, 0, stream>>>(x, embed, words);
    k_transpose<<<dim3(96, 16), dim3(32, 8), 0, stream>>>(w_i, wit, DD, N3H);
    k_transpose<<<dim3(96, 32), dim3(32, 8), 0, stream>>>(w_h, wht, HH, N3H);
    // zero hbuf + rhbuf + flags (contiguous 1048576 + 16384 bytes)
    k_zero<<<261, 256, 0, stream>>>((uint4*)(ws + 126877696), (1048576 + 16384) / 16);
    k_gemm_gx<<<dim3(24, 128), 256, 0, stream>>>(words, wit, bias, gx);
    // L2 shadows + init flags + xcd table alias words -> zero AFTER gemm.
    // (k_zero's normal writes are flushed device-wide at kernel end, so the
    // later agent-scope RMWs/loads see clean zeros.)
    k_zero<<<261, 256, 0, stream>>>((uint4*)(ws + 110100480), (524288 + 524288 + 16384 + 4096) / 16);
    k_recur<<<dim3(8, 32), 256, 48 * (HH + 8) * 2, stream>>>(gx, wht, hbuf, rhbuf,
                                                             hbufL2, rhbufL2, xtab,
                                                             flags, bar2, out);
}

// Round 3
// 957.465 us; speedup vs baseline: 1.3350x; 1.0494x over previous
//
#include <hip/hip_runtime.h>
#include <hip/hip_bf16.h>
#include <stdint.h>

// GRU-style LanguageEncoder: T=64, B=256, VOCAB=32000, D=512, H=1024.
// Reference semantics: a = tanh(a_x + (r * h) @ w_h_a + b_a)  ((r*h) BEFORE matmul).
// Structure:
//   k_gather    : words_bf16[t*B+b][d] = bf16(embed[x]*(x>0))
//   k_transpose : w_i -> wit (3072x512) bf16 ; w_h -> wht (3072x1024) bf16
//   k_zero      : zero h buffer + barrier flags
//   k_gemm_gx   : gx = words @ w_i + b  (16384x3072, bf16), 128x128 MFMA tile
//   k_recur     : persistent 256-block kernel, 64 steps, 2 phases/step.
//   History (per-step): R2 RMW+fences 33us; R3 flags+fences 21.5; R6 atomic
//   reads 16.4 (atomic-pipe-bound); R8 acquire-inv cached reads 12.8;
//   R9/R10 plain sc0sc1 L3 loads + u64 exchange writes, no fences: 12.4.
//   R11 role-split FAILED (17.5): AoS ship writes amplified 5.8x + 4-XCD grid.
//   R12 L2-local read path: fabric reads halved (FETCH 180->98MB), dur
//   UNCHANGED -> slab reads are NOT on the critical path. WRITE_SIZE 67.6MB
//   == exchange volume -> the u64 atomic-exchange RMWs write through to DRAM,
//   and their completion sits inside every phase's arrive drain (vmcnt(0)
//   before flag RMW). THAT is the per-phase floor.
//   R13: data exchanges become plain global_store_dwordx2 sc0 sc1 (write-
//   through to L3 coherence point, normal path, no atomic pipe, no DRAM
//   write-through; single-writer slots need no RMW semantics). Ordering
//   skeleton unchanged: stores vmcnt-drained by __syncthreads before the flag
//   fetch_add; readers poll flags then sc0sc1-read at the same point.
//   Keep R12's counted-vmcnt issue-all slab loads (WAIT8 24/16/8/0); drop the
//   L2-shadow/classify machinery (proven off-path, -36us).

#define TT 64
#define BB 256
#define DD 512
#define HH 1024
#define N3H 3072

using frag  = __attribute__((ext_vector_type(8))) short;   // 8 bf16 (4 VGPRs)
using f32x4 = __attribute__((ext_vector_type(4))) float;   // MFMA accumulator

__device__ __forceinline__ uint16_t f2b(float f) {
    uint32_t u = __builtin_bit_cast(uint32_t, f);
    uint32_t r = u + 0x7FFFu + ((u >> 16) & 1u);   // round-to-nearest-even
    return (uint16_t)(r >> 16);
}
__device__ __forceinline__ float b2f(uint16_t b) {
    uint32_t u = ((uint32_t)b) << 16;
    return __builtin_bit_cast(float, u);
}

// Issue 8 x 16B L3-coherent loads (sc0 sc1: bypass L1/L2, performed at the
// coherence point) from 64B-strided addresses. NO wait - caller uses counted
// vmcnt via WAIT8. gfx950 asm operand order: offset:N BEFORE cache flags.
__device__ __forceinline__ void load8_issue(const uint16_t* p, frag* f) {
    asm volatile(
        "global_load_dwordx4 %0, %8, off sc0 sc1\n\t"
        "global_load_dwordx4 %1, %8, off offset:64 sc0 sc1\n\t"
        "global_load_dwordx4 %2, %8, off offset:128 sc0 sc1\n\t"
        "global_load_dwordx4 %3, %8, off offset:192 sc0 sc1\n\t"
        "global_load_dwordx4 %4, %8, off offset:256 sc0 sc1\n\t"
        "global_load_dwordx4 %5, %8, off offset:320 sc0 sc1\n\t"
        "global_load_dwordx4 %6, %8, off offset:384 sc0 sc1\n\t"
        "global_load_dwordx4 %7, %8, off offset:448 sc0 sc1"
        : "=&v"(f[0]), "=&v"(f[1]), "=&v"(f[2]), "=&v"(f[3]),
          "=&v"(f[4]), "=&v"(f[5]), "=&v"(f[6]), "=&v"(f[7])
        : "v"(p)
        : "memory");
}

// counted wait: outstanding <= N. Ties the 8 frags so MFMA consumers depend
// on THIS asm's outputs (rule-18-safe without sched_barrier).
#define WAIT8(N, F)                                                       \
    asm volatile("s_waitcnt vmcnt(" #N ")"                                \
                 : "+v"((F)[0]), "+v"((F)[1]), "+v"((F)[2]),              \
                   "+v"((F)[3]), "+v"((F)[4]), "+v"((F)[5]),              \
                   "+v"((F)[6]), "+v"((F)[7]))

#define ZCON(KB, HF)                                                              \
    _Pragma("unroll")                                                             \
    for (int j = 0; j < 8; ++j) {                                                 \
        int kk = (KB) * 8 + j;                                                    \
        frag b0 = *(const frag*)(Wh + (l16)      * LDW + kk * 32 + quad * 8);     \
        frag b1 = *(const frag*)(Wh + (16 + l16) * LDW + kk * 32 + quad * 8);     \
        acc0 = __builtin_amdgcn_mfma_f32_16x16x32_bf16((HF)[j], b0, acc0, 0, 0, 0); \
        acc1 = __builtin_amdgcn_mfma_f32_16x16x32_bf16((HF)[j], b1, acc1, 0, 0, 0); \
    }

#define ACON(KB, RF)                                                              \
    _Pragma("unroll")                                                             \
    for (int j = 0; j < 8; ++j) {                                                 \
        int kk = (KB) * 8 + j;                                                    \
        frag b2 = *(const frag*)(Wh + (32 + l16) * LDW + kk * 32 + quad * 8);     \
        acc2 = __builtin_amdgcn_mfma_f32_16x16x32_bf16((RF)[j], b2, acc2, 0, 0, 0); \
    }

// ---------------- prep kernels ----------------

__global__ __launch_bounds__(256) void k_gather(const int* __restrict__ x,
                                                const float* __restrict__ embed,
                                                uint16_t* __restrict__ words) {
    int tid = blockIdx.x * 256 + threadIdx.x;
    int row = tid >> 6;
    int c8  = (tid & 63) << 3;
    int tok = x[row];
    float s = (tok > 0) ? 1.f : 0.f;
    const float4* src = (const float4*)(embed + (int64_t)tok * DD + c8);
    float4 v0 = src[0], v1 = src[1];
    float vals[8] = {v0.x, v0.y, v0.z, v0.w, v1.x, v1.y, v1.z, v1.w};
    union { uint16_t u[8]; uint4 q; } pk;
#pragma unroll
    for (int i = 0; i < 8; ++i) pk.u[i] = f2b(vals[i] * s);
    *(uint4*)(words + ((int64_t)row << 9) + c8) = pk.q;
}

// src (K x N) fp32 -> dst (N x K) bf16, 32x32 LDS tiles
__global__ void k_transpose(const float* __restrict__ src, uint16_t* __restrict__ dst,
                            int K, int N) {
    __shared__ float tile[32][33];
    int n0 = blockIdx.x * 32, k0 = blockIdx.y * 32;
    int tx = threadIdx.x, ty = threadIdx.y;   // (32, 8)
#pragma unroll
    for (int i = 0; i < 32; i += 8)
        tile[ty + i][tx] = src[(int64_t)(k0 + ty + i) * N + n0 + tx];
    __syncthreads();
#pragma unroll
    for (int i = 0; i < 32; i += 8)
        dst[(int64_t)(n0 + ty + i) * K + k0 + tx] = f2b(tile[tx][ty + i]);
}

__global__ void k_zero(uint4* p, int n16) {
    int i = blockIdx.x * blockDim.x + threadIdx.x;
    if (i < n16) p[i] = uint4{0u, 0u, 0u, 0u};
}

// ---------------- gx GEMM: 16384 x 3072 x 512 ----------------

__global__ __launch_bounds__(256) void k_gemm_gx(const uint16_t* __restrict__ A,
                                                 const uint16_t* __restrict__ BT,
                                                 const float* __restrict__ bias,
                                                 uint16_t* __restrict__ C) {
    __shared__ uint16_t As[128][72];
    __shared__ uint16_t Bs[128][72];
    int m0 = blockIdx.y * 128;
    int n0 = blockIdx.x * 128;
    int t = threadIdx.x;
    int wave = t >> 6, lane = t & 63, quad = lane >> 4, l16 = lane & 15;
    int wm = (wave & 1) * 64, wn = (wave >> 1) * 64;
    f32x4 acc[4][4] = {};

    int sr = t >> 1;
    int sc = (t & 1) * 32;

    for (int k0 = 0; k0 < DD; k0 += 64) {
        const uint4* ga = (const uint4*)(A + (int64_t)(m0 + sr) * DD + k0 + sc);
        uint4 a0 = ga[0], a1 = ga[1], a2 = ga[2], a3 = ga[3];
        const uint4* gb = (const uint4*)(BT + (int64_t)(n0 + sr) * DD + k0 + sc);
        uint4 b0 = gb[0], b1 = gb[1], b2 = gb[2], b3 = gb[3];
        __syncthreads();
        *(uint4*)&As[sr][sc]      = a0;
        *(uint4*)&As[sr][sc + 8]  = a1;
        *(uint4*)&As[sr][sc + 16] = a2;
        *(uint4*)&As[sr][sc + 24] = a3;
        *(uint4*)&Bs[sr][sc]      = b0;
        *(uint4*)&Bs[sr][sc + 8]  = b1;
        *(uint4*)&Bs[sr][sc + 16] = b2;
        *(uint4*)&Bs[sr][sc + 24] = b3;
        __syncthreads();
#pragma unroll
        for (int kk = 0; kk < 64; kk += 32) {
            frag af[4], bf[4];
#pragma unroll
            for (int mi = 0; mi < 4; ++mi)
                af[mi] = *(const frag*)&As[wm + mi * 16 + l16][kk + quad * 8];
#pragma unroll
            for (int ni = 0; ni < 4; ++ni)
                bf[ni] = *(const frag*)&Bs[wn + ni * 16 + l16][kk + quad * 8];
#pragma unroll
            for (int mi = 0; mi < 4; ++mi)
#pragma unroll
                for (int ni = 0; ni < 4; ++ni)
                    acc[mi][ni] = __builtin_amdgcn_mfma_f32_16x16x32_bf16(
                        af[mi], bf[ni], acc[mi][ni], 0, 0, 0);
        }
    }
#pragma unroll
    for (int ni = 0; ni < 4; ++ni) {
        int col = n0 + wn + ni * 16 + l16;
        float bv = bias[col];
#pragma unroll
        for (int mi = 0; mi < 4; ++mi)
#pragma unroll
            for (int r = 0; r < 4; ++r) {
                int row = m0 + wm + mi * 16 + quad * 4 + r;
                C[(int64_t)row * N3H + col] = f2b(acc[mi][ni][r] + bv);
            }
    }
}

// ---------------- recurrence (R13) ----------------
// grid (mg=4, jb=64): linear id = mg + 4*jb -> each m-group's 64 blocks sit on
// XCDs {mg, mg+4} (i%8 round-robin). LDS: Wh[48][1032] bf16 (99KB).
// Flags: one 4B slot per block, 64B apart; group mg owns bar[mg*1024 + jb*16].

__global__ __launch_bounds__(256, 1) void k_recur(const uint16_t* __restrict__ gx,
                                                  const uint16_t* __restrict__ wht,
                                                  uint16_t* __restrict__ hbuf,
                                                  uint16_t* __restrict__ rhbuf,
                                                  unsigned int* __restrict__ bar,
                                                  float* __restrict__ out) {
    extern __shared__ uint16_t Wh[];           // 48 rows x 1032 (1024 + 8 pad)
    const int LDW = HH + 8;
    int mg = blockIdx.x;        // 0..3  (fast dim -> XCD pairing)
    int jb = blockIdx.y;        // 0..63
    int j0 = jb * 16;
    int m0 = mg * 64;
    int t = threadIdx.x, wave = t >> 6, lane = t & 63, quad = lane >> 4, l16 = lane & 15;

    // load w_h slice: gathered rows s*16+i  <-  wht row s*HH + j0 + i
    for (int c = t; c < 48 * 128; c += 256) {
        int row = c >> 7;
        int off = (c & 127) << 3;
        int s = row >> 4, i = row & 15;
        *(uint4*)(Wh + row * LDW + off) =
            *(const uint4*)(wht + (int64_t)(s * HH + j0 + i) * HH + off);
    }
    __syncthreads();

    float hp[4]   = {0.f, 0.f, 0.f, 0.f};
    float zg[4];
    float osum[4] = {0.f, 0.f, 0.f, 0.f};
    int brow = m0 + wave * 16 + quad * 4;
    int jcol = j0 + l16;
    const int jc4 = j0 + (l16 & ~3);         // 4-col pack base
    unsigned int* flags = bar + mg * 1024;   // 64 slots x 64B stride
    unsigned int phase = 0;

    // A-operand bases (this lane's MFMA A rows) - read via sc0sc1 L3 loads
    const uint16_t* harow  = hbuf  + (int64_t)(m0 + wave * 16 + l16) * HH + quad * 8;
    const uint16_t* rharow = rhbuf + (int64_t)(m0 + wave * 16 + l16) * HH + quad * 8;

    // arrive: drain my data stores (syncthreads -> vmcnt(0)), then RMW my flag.
    auto bar_arrive = [&]() {
        __syncthreads();
        if (t == 0)
            (void)__hip_atomic_fetch_add(&flags[jb * 16], 1u, __ATOMIC_RELAXED,
                                         __HIP_MEMORY_SCOPE_AGENT);
    };
    // wait: wave0 polls all 64 slots in parallel with relaxed loads.
    // No fence after: h/rh reads bypass L1/L2 (sc0sc1), gx is immutable.
    auto bar_wait = [&](unsigned int ph) {
        if (wave == 0) {
            long guard = 0;
            for (;;) {
                unsigned int v = __hip_atomic_load(&flags[lane * 16], __ATOMIC_RELAXED,
                                                   __HIP_MEMORY_SCOPE_AGENT);
                if (__all((int)(v >= ph))) break;
                __builtin_amdgcn_s_sleep(1);
                if (++guard > (1L << 13)) break;   // fail fast (absmax), never wedge
            }
        }
        __syncthreads();
    };

    // pack this lane's value with lanes l16^1, l16^2 -> one uint64 (4 adjacent
    // cols), written by the (l16%4==0) lane as a PLAIN sc0sc1 store: write-
    // through to the L3 coherence point on the normal path (no atomic pipe,
    // no DRAM write-through). Single-writer slots; vmcnt-drained before flag.
    auto store4 = [&](uint16_t* base, int r, uint32_t mine) {
        uint32_t p2 = mine | (((uint32_t)__shfl_xor((int)mine, 1)) << 16);
        uint32_t hi = (uint32_t)__shfl_xor((int)p2, 2);
        if ((l16 & 3) == 0) {
            uint64_t p4 = (uint64_t)p2 | ((uint64_t)hi << 32);
            uint64_t* dst = (uint64_t*)base + (int64_t)(brow + r) * (HH / 4) + (jc4 >> 2);
            asm volatile("global_store_dwordx2 %0, %1, off sc0 sc1"
                         :: "v"(dst), "v"(p4) : "memory");
        }
    };

    for (int step = 0; step < TT; ++step) {
        // ---- barrier: h(step) fully written by all blocks in m-group ----
        if (step > 0) bar_arrive();

        // prefetch this step's gx scalars (immutable, cached; L2 stays warm all
        // 128 phases) - issued between arrive and wait to hide under the poll
        uint16_t gzv[4], grv[4], gav[4];
        {
            const uint16_t* gxrow = gx + (int64_t)step * BB * N3H;
#pragma unroll
            for (int r = 0; r < 4; ++r) {
                const uint16_t* g = gxrow + (int64_t)(brow + r) * N3H + jcol;
                gzv[r] = g[0]; grv[r] = g[HH]; gav[r] = g[2 * HH];
            }
        }

        if (step > 0) bar_wait(++phase);
        asm volatile("s_waitcnt vmcnt(0)" ::: "memory");   // clean vmcnt slate

        // ---- phase Z: h @ w_h_zr (acc0 = z-col, acc1 = r-col) ----
        {
            frag h0[8], h1[8], h2[8], h3[8];
            load8_issue(harow,       h0);
            load8_issue(harow + 256, h1);
            load8_issue(harow + 512, h2);
            load8_issue(harow + 768, h3);
            f32x4 acc0 = {}, acc1 = {};
            WAIT8(24, h0); ZCON(0, h0);
            WAIT8(16, h1); ZCON(1, h1);
            WAIT8(8,  h2); ZCON(2, h2);
            WAIT8(0,  h3); ZCON(3, h3);
#pragma unroll
            for (int r = 0; r < 4; ++r) {
                float zp = b2f(gzv[r]) + acc0[r];        // bias folded into gx
                float rp = b2f(grv[r]) + acc1[r];
                float z  = 1.f / (1.f + __expf(-zp));
                float rg = 1.f / (1.f + __expf(-rp));
                zg[r] = z;
                store4(rhbuf, r, (uint32_t)f2b(rg * hp[r]));
            }
        }

        // ---- barrier: rh fully written by all blocks in m-group ----
        bar_arrive();
        bar_wait(++phase);
        asm volatile("s_waitcnt vmcnt(0)" ::: "memory");   // clean vmcnt slate

        // ---- phase A: rh @ w_h_a (acc2), gate + h update ----
        {
            frag rf0[8], rf1[8], rf2[8], rf3[8];
            load8_issue(rharow,       rf0);
            load8_issue(rharow + 256, rf1);
            load8_issue(rharow + 512, rf2);
            load8_issue(rharow + 768, rf3);
            f32x4 acc2 = {};
            WAIT8(24, rf0); ACON(0, rf0);
            WAIT8(16, rf1); ACON(1, rf1);
            WAIT8(8,  rf2); ACON(2, rf2);
            WAIT8(0,  rf3); ACON(3, rf3);
#pragma unroll
            for (int r = 0; r < 4; ++r) {
                float a  = tanhf(b2f(gav[r]) + acc2[r]);
                float hn = (1.f - zg[r]) * hp[r] + zg[r] * a;
                osum[r] += hn;
                hp[r] = hn;
                store4(hbuf, r, (uint32_t)f2b(hn));
            }
        }
    }
#pragma unroll
    for (int r = 0; r < 4; ++r)
        out[(int64_t)(brow + r) * HH + jcol] = osum[r];
}

// ---------------- launch ----------------

extern "C" void kernel_launch(void* const* d_in, const int* in_sizes, int n_in,
                              void* d_out, int out_size, void* d_ws, size_t ws_size,
                              hipStream_t stream) {
    const int*   x     = (const int*)d_in[0];
    const float* embed = (const float*)d_in[1];
    const float* w_i   = (const float*)d_in[2];
    const float* w_h   = (const float*)d_in[3];
    const float* bias  = (const float*)d_in[4];
    float* out = (float*)d_out;

    char* ws = (char*)d_ws;
    uint16_t* gx    = (uint16_t*)(ws);                 // 16384*3072*2 = 100663296
    uint16_t* wit   = (uint16_t*)(ws + 100663296);     // 3072*512*2  =   3145728
    uint16_t* wht   = (uint16_t*)(ws + 103809024);     // 3072*1024*2 =   6291456
    uint16_t* words = (uint16_t*)(ws + 110100480);     // 16384*512*2 =  16777216
    uint16_t* hbuf  = (uint16_t*)(ws + 126877696);     // 256*1024*2  =    524288
    uint16_t* rhbuf = (uint16_t*)(ws + 127401984);     // 256*1024*2  =    524288
    unsigned int* flags = (unsigned int*)(ws + 127926272); // 4*1024*4 = 16384

    k_gather<<<4096, 256, 0, stream>>>(x, embed, words);
    k_transpose<<<dim3(96, 16), dim3(32, 8), 0, stream>>>(w_i, wit, DD, N3H);
    k_transpose<<<dim3(96, 32), dim3(32, 8), 0, stream>>>(w_h, wht, HH, N3H);
    // zero hbuf + rhbuf + flags (contiguous 1048576 + 16384 bytes)
    k_zero<<<261, 256, 0, stream>>>((uint4*)(ws + 126877696), (1048576 + 16384) / 16);
    k_gemm_gx<<<dim3(24, 128), 256, 0, stream>>>(words, wit, bias, gx);
    k_recur<<<dim3(4, 64), 256, 48 * (HH + 8) * 2, stream>>>(gx, wht, hbuf, rhbuf, flags, out);
}

// Round 4
// 892.677 us; speedup vs baseline: 1.4319x; 1.0726x over previous
//
#include <hip/hip_runtime.h>
#include <hip/hip_bf16.h>
#include <stdint.h>

// GRU-style LanguageEncoder: T=64, B=256, VOCAB=32000, D=512, H=1024.
// Reference semantics: a = tanh(a_x + (r * h) @ w_h_a + b_a)  ((r*h) BEFORE matmul).
// Structure:
//   k_gather    : words_bf16[t*B+b][d] = bf16(embed[x]*(x>0))
//   k_transpose : w_i -> wit (3072x512) bf16 ; w_h -> wht (3072x1024) bf16
//   k_zero      : zero h buffer + barrier flags (+ rot slot 0)
//   k_gemm_gx   : gx = words @ w_i + b  (16384x3072, bf16), 128x128 MFMA tile
//   k_recur     : persistent 256-block kernel, 64 steps, 2 phases/step.
//   History (per-step): R2 RMW+fences 33us; R3 flags+fences 21.5; R6 atomic
//   reads 16.4; R8 acquire-inv cached reads 12.8 (~5us/phase = inv L2-walk,
//   => cached-path phase cost ~1.4us); R9/R10 sc0sc1 bypass reads 12.4.
//   R11 role-split FAILED (confounded). R12 L2-local reads: fabric reads
//   halved, dur UNCHANGED. R13 plain-store exchange: WRITE_SIZE and dur
//   IDENTICAL to R10. Conclusion: the 6.2us/phase floor is the per-CU
//   L1/L2-BYPASS read-request path (~2048 64B segments/CU/phase at ~7cy),
//   not fabric BW, not store class, not DRAM. The fast path is the NORMAL
//   cached path (R8: ~1.4us/phase) - its blocker was the 5us invalidate.
//   R14: ROTATING exchange buffers -> cached reads with ZERO invalidates.
//   One fresh 512KB slab per step (65 h slots + 64 rh slots, +64.5MB ws).
//   Every exchange address is read exactly once per reader CU -> first touch
//   -> guaranteed L1/L2 miss -> fresh fetch from L3 on the cached path;
//   same-XCD readers share one L3->L2 fetch. Writes stay sc0sc1 write-through
//   (dirty-in-L2 would be invisible cross-XCD). Barrier skeleton unchanged.
//   Launcher checks ws_size and falls back to the exact R13 kernel if the
//   rotation region does not fit.

#define TT 64
#define BB 256
#define DD 512
#define HH 1024
#define N3H 3072
#define SLAB (BB * HH)   // elements per h/rh snapshot (512 KB)

using frag  = __attribute__((ext_vector_type(8))) short;   // 8 bf16 (4 VGPRs)
using f32x4 = __attribute__((ext_vector_type(4))) float;   // MFMA accumulator

__device__ __forceinline__ uint16_t f2b(float f) {
    uint32_t u = __builtin_bit_cast(uint32_t, f);
    uint32_t r = u + 0x7FFFu + ((u >> 16) & 1u);   // round-to-nearest-even
    return (uint16_t)(r >> 16);
}
__device__ __forceinline__ float b2f(uint16_t b) {
    uint32_t u = ((uint32_t)b) << 16;
    return __builtin_bit_cast(float, u);
}

// Issue 8 x 16B L3-coherent loads (sc0 sc1: bypass L1/L2) from 64B-strided
// addresses. NO wait - caller uses counted vmcnt via WAIT8. (Fallback path.)
__device__ __forceinline__ void load8_issue(const uint16_t* p, frag* f) {
    asm volatile(
        "global_load_dwordx4 %0, %8, off sc0 sc1\n\t"
        "global_load_dwordx4 %1, %8, off offset:64 sc0 sc1\n\t"
        "global_load_dwordx4 %2, %8, off offset:128 sc0 sc1\n\t"
        "global_load_dwordx4 %3, %8, off offset:192 sc0 sc1\n\t"
        "global_load_dwordx4 %4, %8, off offset:256 sc0 sc1\n\t"
        "global_load_dwordx4 %5, %8, off offset:320 sc0 sc1\n\t"
        "global_load_dwordx4 %6, %8, off offset:384 sc0 sc1\n\t"
        "global_load_dwordx4 %7, %8, off offset:448 sc0 sc1"
        : "=&v"(f[0]), "=&v"(f[1]), "=&v"(f[2]), "=&v"(f[3]),
          "=&v"(f[4]), "=&v"(f[5]), "=&v"(f[6]), "=&v"(f[7])
        : "v"(p)
        : "memory");
}

#define WAIT8(N, F)                                                       \
    asm volatile("s_waitcnt vmcnt(" #N ")"                                \
                 : "+v"((F)[0]), "+v"((F)[1]), "+v"((F)[2]),              \
                   "+v"((F)[3]), "+v"((F)[4]), "+v"((F)[5]),              \
                   "+v"((F)[6]), "+v"((F)[7]))

#define ZCON(KB, HF)                                                              \
    _Pragma("unroll")                                                             \
    for (int j = 0; j < 8; ++j) {                                                 \
        int kk = (KB) * 8 + j;                                                    \
        frag b0 = *(const frag*)(Wh + (l16)      * LDW + kk * 32 + quad * 8);     \
        frag b1 = *(const frag*)(Wh + (16 + l16) * LDW + kk * 32 + quad * 8);     \
        acc0 = __builtin_amdgcn_mfma_f32_16x16x32_bf16((HF)[j], b0, acc0, 0, 0, 0); \
        acc1 = __builtin_amdgcn_mfma_f32_16x16x32_bf16((HF)[j], b1, acc1, 0, 0, 0); \
    }

#define ACON(KB, RF)                                                              \
    _Pragma("unroll")                                                             \
    for (int j = 0; j < 8; ++j) {                                                 \
        int kk = (KB) * 8 + j;                                                    \
        frag b2 = *(const frag*)(Wh + (32 + l16) * LDW + kk * 32 + quad * 8);     \
        acc2 = __builtin_amdgcn_mfma_f32_16x16x32_bf16((RF)[j], b2, acc2, 0, 0, 0); \
    }

// ---------------- prep kernels ----------------

__global__ __launch_bounds__(256) void k_gather(const int* __restrict__ x,
                                                const float* __restrict__ embed,
                                                uint16_t* __restrict__ words) {
    int tid = blockIdx.x * 256 + threadIdx.x;
    int row = tid >> 6;
    int c8  = (tid & 63) << 3;
    int tok = x[row];
    float s = (tok > 0) ? 1.f : 0.f;
    const float4* src = (const float4*)(embed + (int64_t)tok * DD + c8);
    float4 v0 = src[0], v1 = src[1];
    float vals[8] = {v0.x, v0.y, v0.z, v0.w, v1.x, v1.y, v1.z, v1.w};
    union { uint16_t u[8]; uint4 q; } pk;
#pragma unroll
    for (int i = 0; i < 8; ++i) pk.u[i] = f2b(vals[i] * s);
    *(uint4*)(words + ((int64_t)row << 9) + c8) = pk.q;
}

// src (K x N) fp32 -> dst (N x K) bf16, 32x32 LDS tiles
__global__ void k_transpose(const float* __restrict__ src, uint16_t* __restrict__ dst,
                            int K, int N) {
    __shared__ float tile[32][33];
    int n0 = blockIdx.x * 32, k0 = blockIdx.y * 32;
    int tx = threadIdx.x, ty = threadIdx.y;   // (32, 8)
#pragma unroll
    for (int i = 0; i < 32; i += 8)
        tile[ty + i][tx] = src[(int64_t)(k0 + ty + i) * N + n0 + tx];
    __syncthreads();
#pragma unroll
    for (int i = 0; i < 32; i += 8)
        dst[(int64_t)(n0 + ty + i) * K + k0 + tx] = f2b(tile[tx][ty + i]);
}

__global__ void k_zero(uint4* p, int n16) {
    int i = blockIdx.x * blockDim.x + threadIdx.x;
    if (i < n16) p[i] = uint4{0u, 0u, 0u, 0u};
}

// ---------------- gx GEMM: 16384 x 3072 x 512 ----------------

__global__ __launch_bounds__(256) void k_gemm_gx(const uint16_t* __restrict__ A,
                                                 const uint16_t* __restrict__ BT,
                                                 const float* __restrict__ bias,
                                                 uint16_t* __restrict__ C) {
    __shared__ uint16_t As[128][72];
    __shared__ uint16_t Bs[128][72];
    int m0 = blockIdx.y * 128;
    int n0 = blockIdx.x * 128;
    int t = threadIdx.x;
    int wave = t >> 6, lane = t & 63, quad = lane >> 4, l16 = lane & 15;
    int wm = (wave & 1) * 64, wn = (wave >> 1) * 64;
    f32x4 acc[4][4] = {};

    int sr = t >> 1;
    int sc = (t & 1) * 32;

    for (int k0 = 0; k0 < DD; k0 += 64) {
        const uint4* ga = (const uint4*)(A + (int64_t)(m0 + sr) * DD + k0 + sc);
        uint4 a0 = ga[0], a1 = ga[1], a2 = ga[2], a3 = ga[3];
        const uint4* gb = (const uint4*)(BT + (int64_t)(n0 + sr) * DD + k0 + sc);
        uint4 b0 = gb[0], b1 = gb[1], b2 = gb[2], b3 = gb[3];
        __syncthreads();
        *(uint4*)&As[sr][sc]      = a0;
        *(uint4*)&As[sr][sc + 8]  = a1;
        *(uint4*)&As[sr][sc + 16] = a2;
        *(uint4*)&As[sr][sc + 24] = a3;
        *(uint4*)&Bs[sr][sc]      = b0;
        *(uint4*)&Bs[sr][sc + 8]  = b1;
        *(uint4*)&Bs[sr][sc + 16] = b2;
        *(uint4*)&Bs[sr][sc + 24] = b3;
        __syncthreads();
#pragma unroll
        for (int kk = 0; kk < 64; kk += 32) {
            frag af[4], bf[4];
#pragma unroll
            for (int mi = 0; mi < 4; ++mi)
                af[mi] = *(const frag*)&As[wm + mi * 16 + l16][kk + quad * 8];
#pragma unroll
            for (int ni = 0; ni < 4; ++ni)
                bf[ni] = *(const frag*)&Bs[wn + ni * 16 + l16][kk + quad * 8];
#pragma unroll
            for (int mi = 0; mi < 4; ++mi)
#pragma unroll
                for (int ni = 0; ni < 4; ++ni)
                    acc[mi][ni] = __builtin_amdgcn_mfma_f32_16x16x32_bf16(
                        af[mi], bf[ni], acc[mi][ni], 0, 0, 0);
        }
    }
#pragma unroll
    for (int ni = 0; ni < 4; ++ni) {
        int col = n0 + wn + ni * 16 + l16;
        float bv = bias[col];
#pragma unroll
        for (int mi = 0; mi < 4; ++mi)
#pragma unroll
            for (int r = 0; r < 4; ++r) {
                int row = m0 + wm + mi * 16 + quad * 4 + r;
                C[(int64_t)row * N3H + col] = f2b(acc[mi][ni][r] + bv);
            }
    }
}

// ---------------- recurrence (R14) ----------------
// grid (mg=4, jb=64): linear id = mg + 4*jb -> each m-group's 64 blocks sit on
// XCDs {mg, mg+4}. LDS: Wh[48][1032] bf16 (99KB).
// ROT=1: hb/rb are rotation bases. h slot s = state before step s (slot 0
// zeroed); Z(t) reads slot t (cached, first-touch), A(t) writes slot t+1
// (sc0sc1). rh slot t written in Z(t), read cached in A(t). 65+64 slots.
// ROT=0: exact R13 static-buffer behavior (sc0sc1 bypass reads).

template <bool ROT>
__global__ __launch_bounds__(256, 1) void k_recur(const uint16_t* __restrict__ gx,
                                                  const uint16_t* __restrict__ wht,
                                                  uint16_t* __restrict__ hb,
                                                  uint16_t* __restrict__ rb,
                                                  unsigned int* __restrict__ bar,
                                                  float* __restrict__ out) {
    extern __shared__ uint16_t Wh[];           // 48 rows x 1032 (1024 + 8 pad)
    const int LDW = HH + 8;
    int mg = blockIdx.x;        // 0..3  (fast dim -> XCD pairing)
    int jb = blockIdx.y;        // 0..63
    int j0 = jb * 16;
    int m0 = mg * 64;
    int t = threadIdx.x, wave = t >> 6, lane = t & 63, quad = lane >> 4, l16 = lane & 15;

    // load w_h slice: gathered rows s*16+i  <-  wht row s*HH + j0 + i
    for (int c = t; c < 48 * 128; c += 256) {
        int row = c >> 7;
        int off = (c & 127) << 3;
        int s = row >> 4, i = row & 15;
        *(uint4*)(Wh + row * LDW + off) =
            *(const uint4*)(wht + (int64_t)(s * HH + j0 + i) * HH + off);
    }
    __syncthreads();

    float hp[4]   = {0.f, 0.f, 0.f, 0.f};
    float zg[4];
    float osum[4] = {0.f, 0.f, 0.f, 0.f};
    int brow = m0 + wave * 16 + quad * 4;
    int jcol = j0 + l16;
    const int jc4 = j0 + (l16 & ~3);         // 4-col pack base
    unsigned int* flags = bar + mg * 1024;   // 64 slots x 64B stride
    unsigned int phase = 0;

    // this lane's MFMA A-row offset within a slab
    const int64_t arow = (int64_t)(m0 + wave * 16 + l16) * HH + quad * 8;

    auto bar_arrive = [&]() {
        __syncthreads();   // compiler emits vmcnt(0) drain before s_barrier
        if (t == 0)
            (void)__hip_atomic_fetch_add(&flags[jb * 16], 1u, __ATOMIC_RELAXED,
                                         __HIP_MEMORY_SCOPE_AGENT);
    };
    auto bar_wait = [&](unsigned int ph) {
        if (wave == 0) {
            long guard = 0;
            for (;;) {
                unsigned int v = __hip_atomic_load(&flags[lane * 16], __ATOMIC_RELAXED,
                                                   __HIP_MEMORY_SCOPE_AGENT);
                if (__all((int)(v >= ph))) break;
                __builtin_amdgcn_s_sleep(1);
                if (++guard > (1L << 13)) break;   // fail fast (absmax), never wedge
            }
        }
        __syncthreads();
    };

    // pack lanes l16^1, l16^2 -> one uint64 (4 adjacent cols), written by the
    // (l16%4==0) lane as a plain sc0sc1 store (write-through to L3; required
    // for cross-XCD visibility). vmcnt-drained before the flag RMW.
    auto store4 = [&](uint16_t* base, int r, uint32_t mine) {
        uint32_t p2 = mine | (((uint32_t)__shfl_xor((int)mine, 1)) << 16);
        uint32_t hi = (uint32_t)__shfl_xor((int)p2, 2);
        if ((l16 & 3) == 0) {
            uint64_t p4 = (uint64_t)p2 | ((uint64_t)hi << 32);
            uint64_t* dst = (uint64_t*)base + (int64_t)(brow + r) * (HH / 4) + (jc4 >> 2);
            asm volatile("global_store_dwordx2 %0, %1, off sc0 sc1"
                         :: "v"(dst), "v"(p4) : "memory");
        }
    };

    for (int step = 0; step < TT; ++step) {
        const uint16_t* hsrc;  uint16_t* rhdst;
        const uint16_t* rhsrc; uint16_t* hdst;
        if constexpr (ROT) {
            hsrc  = hb + (size_t)step * SLAB;        // state before this step
            hdst  = hb + (size_t)(step + 1) * SLAB;
            rhsrc = rb + (size_t)step * SLAB;
            rhdst = rb + (size_t)step * SLAB;
        } else {
            hsrc = hb; hdst = hb; rhsrc = rb; rhdst = rb;
        }

        // ---- barrier: h(step) fully written by all blocks in m-group ----
        if (step > 0) bar_arrive();

        // prefetch this step's gx scalars (immutable, cached) - issued between
        // arrive and wait to hide under the poll
        uint16_t gzv[4], grv[4], gav[4];
        {
            const uint16_t* gxrow = gx + (int64_t)step * BB * N3H;
#pragma unroll
            for (int r = 0; r < 4; ++r) {
                const uint16_t* g = gxrow + (int64_t)(brow + r) * N3H + jcol;
                gzv[r] = g[0]; grv[r] = g[HH]; gav[r] = g[2 * HH];
            }
        }

        if (step > 0) bar_wait(++phase);

        // ---- phase Z: h @ w_h_zr (acc0 = z-col, acc1 = r-col) ----
        {
            f32x4 acc0 = {}, acc1 = {};
            if constexpr (ROT) {
                const uint16_t* hrow = hsrc + arow;
#pragma unroll
                for (int kb = 0; kb < 4; ++kb) {
                    frag hf[8];
#pragma unroll
                    for (int j = 0; j < 8; ++j)
                        hf[j] = *(const frag*)(hrow + kb * 256 + j * 32);
                    ZCON(kb, hf);
                }
            } else {
                asm volatile("s_waitcnt vmcnt(0)" ::: "memory");
                const uint16_t* hrow = hsrc + arow;
                frag h0[8], h1[8], h2[8], h3[8];
                load8_issue(hrow,       h0);
                load8_issue(hrow + 256, h1);
                load8_issue(hrow + 512, h2);
                load8_issue(hrow + 768, h3);
                WAIT8(24, h0); ZCON(0, h0);
                WAIT8(16, h1); ZCON(1, h1);
                WAIT8(8,  h2); ZCON(2, h2);
                WAIT8(0,  h3); ZCON(3, h3);
            }
#pragma unroll
            for (int r = 0; r < 4; ++r) {
                float zp = b2f(gzv[r]) + acc0[r];        // bias folded into gx
                float rp = b2f(grv[r]) + acc1[r];
                float z  = 1.f / (1.f + __expf(-zp));
                float rg = 1.f / (1.f + __expf(-rp));
                zg[r] = z;
                store4(rhdst, r, (uint32_t)f2b(rg * hp[r]));
            }
        }

        // ---- barrier: rh fully written by all blocks in m-group ----
        bar_arrive();
        bar_wait(++phase);

        // ---- phase A: rh @ w_h_a (acc2), gate + h update ----
        {
            f32x4 acc2 = {};
            if constexpr (ROT) {
                const uint16_t* rrow = rhsrc + arow;
#pragma unroll
                for (int kb = 0; kb < 4; ++kb) {
                    frag rf[8];
#pragma unroll
                    for (int j = 0; j < 8; ++j)
                        rf[j] = *(const frag*)(rrow + kb * 256 + j * 32);
                    ACON(kb, rf);
                }
            } else {
                asm volatile("s_waitcnt vmcnt(0)" ::: "memory");
                const uint16_t* rrow = rhsrc + arow;
                frag rf0[8], rf1[8], rf2[8], rf3[8];
                load8_issue(rrow,       rf0);
                load8_issue(rrow + 256, rf1);
                load8_issue(rrow + 512, rf2);
                load8_issue(rrow + 768, rf3);
                WAIT8(24, rf0); ACON(0, rf0);
                WAIT8(16, rf1); ACON(1, rf1);
                WAIT8(8,  rf2); ACON(2, rf2);
                WAIT8(0,  rf3); ACON(3, rf3);
            }
#pragma unroll
            for (int r = 0; r < 4; ++r) {
                float a  = tanhf(b2f(gav[r]) + acc2[r]);
                float hn = (1.f - zg[r]) * hp[r] + zg[r] * a;
                osum[r] += hn;
                hp[r] = hn;
                store4(hdst, r, (uint32_t)f2b(hn));
            }
        }
    }
#pragma unroll
    for (int r = 0; r < 4; ++r)
        out[(int64_t)(brow + r) * HH + jcol] = osum[r];
}

// ---------------- launch ----------------

extern "C" void kernel_launch(void* const* d_in, const int* in_sizes, int n_in,
                              void* d_out, int out_size, void* d_ws, size_t ws_size,
                              hipStream_t stream) {
    const int*   x     = (const int*)d_in[0];
    const float* embed = (const float*)d_in[1];
    const float* w_i   = (const float*)d_in[2];
    const float* w_h   = (const float*)d_in[3];
    const float* bias  = (const float*)d_in[4];
    float* out = (float*)d_out;

    char* ws = (char*)d_ws;
    uint16_t* gx    = (uint16_t*)(ws);                 // 16384*3072*2 = 100663296
    uint16_t* wit   = (uint16_t*)(ws + 100663296);     // 3072*512*2  =   3145728
    uint16_t* wht   = (uint16_t*)(ws + 103809024);     // 3072*1024*2 =   6291456
    uint16_t* words = (uint16_t*)(ws + 110100480);     // 16384*512*2 =  16777216
    uint16_t* hbuf  = (uint16_t*)(ws + 126877696);     // 256*1024*2  =    524288
    uint16_t* rhbuf = (uint16_t*)(ws + 127401984);     // 256*1024*2  =    524288
    unsigned int* flags = (unsigned int*)(ws + 127926272); // 4*1024*4 = 16384
    // rotation region (R14): 65 h slots + 64 rh slots of 512KB
    const size_t ROT_BASE = 127942656;                 // 16KB-aligned
    uint16_t* hrot  = (uint16_t*)(ws + ROT_BASE);                    // 65*524288
    uint16_t* rhrot = (uint16_t*)(ws + ROT_BASE + 65ull * 524288);   // 64*524288
    const size_t ROT_NEED = ROT_BASE + (65ull + 64ull) * 524288;     // 195575808
    const bool rot = ws_size >= ROT_NEED;

    k_gather<<<4096, 256, 0, stream>>>(x, embed, words);
    k_transpose<<<dim3(96, 16), dim3(32, 8), 0, stream>>>(w_i, wit, DD, N3H);
    k_transpose<<<dim3(96, 32), dim3(32, 8), 0, stream>>>(w_h, wht, HH, N3H);
    // zero static hbuf + rhbuf + flags (contiguous 1048576 + 16384 bytes)
    k_zero<<<261, 256, 0, stream>>>((uint4*)(ws + 126877696), (1048576 + 16384) / 16);
    if (rot)   // zero h rotation slot 0 (state before step 0)
        k_zero<<<128, 256, 0, stream>>>((uint4*)hrot, 524288 / 16);
    k_gemm_gx<<<dim3(24, 128), 256, 0, stream>>>(words, wit, bias, gx);
    if (rot)
        k_recur<true><<<dim3(4, 64), 256, 48 * (HH + 8) * 2, stream>>>(
            gx, wht, hrot, rhrot, flags, out);
    else
        k_recur<false><<<dim3(4, 64), 256, 48 * (HH + 8) * 2, stream>>>(
            gx, wht, hbuf, rhbuf, flags, out);
}